// Round 1
// baseline (213711.279 us; speedup 1.0000x reference)
//
#include <hip/hip_runtime.h>
#include <math.h>

// ---------------- model constants ----------------
#define NL 4
#define NH 128
#define FC 16
#define HP 32
#define WP 32
#define BB 8
#define TT 19      // generated frames
#define TPREV 10
#define PLANE 1024 // 32*32

__device__ __forceinline__ float sigmoidf_(float x) { return 1.0f / (1.0f + expf(-x)); }

// ---------------------------------------------------------------
// Implicit-GEMM conv (stride 1, SAME). KS = 5 or 1.
//   in : [B, Cin, 32, 32] f32
//   wgt: [Cout, Cin*KS*KS] f32 row-major (OIHW flattened)
//   out: [B, cout_stride, 32, 32], channels written at co_off + co
// remap=1: co >= 384 -> co + 384 (h-conv o-gate relocation)
// Tile: M=128 (Cout), N=128 (B*H*W), BK=8; 256 thr, 8x8 microtile.
// ---------------------------------------------------------------
template<int KS>
__global__ __launch_bounds__(256) void conv_gemm_kernel(
    const float* __restrict__ in, const float* __restrict__ wgt,
    float* __restrict__ out, int Cin, int co_off, int cout_stride,
    int accumulate, int remap)
{
    const int K = Cin * KS * KS;
    const int tid = threadIdx.x;
    const int n0 = blockIdx.x * 128;
    const int co0 = blockIdx.y * 128;

    __shared__ float As[8][128];
    __shared__ float Bs[8][128];

    const int trow = tid >> 4;   // 0..15 -> m micro-row
    const int tcol = tid & 15;   // 0..15 -> n micro-col

    // A staging: thread -> (m = tid>>1, k4 = (tid&1)*4), float4 along K
    const int a_m  = tid >> 1;
    const int a_k4 = (tid & 1) << 2;
    const float* aptr = wgt + (size_t)(co0 + a_m) * K + a_k4;

    // B staging: thread -> (n = tid&127, 4 k's at (tid>>7)*4)
    const int b_n  = tid & 127;
    const int b_kb = (tid >> 7) << 2;
    const int ng = n0 + b_n;
    const int bidx = ng >> 10;          // batch (constant per block)
    const int pp = ng & 1023;
    const int yy = pp >> 5;
    const int xx = pp & 31;
    const float* inb = in + ((size_t)bidx * Cin << 10);

    float acc[8][8];
#pragma unroll
    for (int i = 0; i < 8; ++i)
#pragma unroll
        for (int j = 0; j < 8; ++j) acc[i][j] = 0.f;

    for (int k0 = 0; k0 < K; k0 += 8) {
        const float4 av = *(const float4*)(aptr + k0);
        float bv[4];
#pragma unroll
        for (int j = 0; j < 4; ++j) {
            const int kg = k0 + b_kb + j;
            int ci, iy, ix;
            bool ok;
            if (KS == 5) {
                ci = kg / 25;
                const int r = kg - ci * 25;
                const int ky = r / 5;
                const int kx = r - ky * 5;
                iy = yy + ky - 2;
                ix = xx + kx - 2;
                ok = ((unsigned)iy < 32u) && ((unsigned)ix < 32u);
            } else {
                ci = kg; iy = yy; ix = xx; ok = true;
            }
            bv[j] = ok ? inb[(ci << 10) + (iy << 5) + ix] : 0.f;
        }
        __syncthreads();
        As[a_k4 + 0][a_m] = av.x;
        As[a_k4 + 1][a_m] = av.y;
        As[a_k4 + 2][a_m] = av.z;
        As[a_k4 + 3][a_m] = av.w;
#pragma unroll
        for (int j = 0; j < 4; ++j) Bs[b_kb + j][b_n] = bv[j];
        __syncthreads();
#pragma unroll
        for (int kk = 0; kk < 8; ++kk) {
            float a[8], b[8];
            *(float4*)(a)     = *(const float4*)&As[kk][trow * 8];
            *(float4*)(a + 4) = *(const float4*)&As[kk][trow * 8 + 4];
            *(float4*)(b)     = *(const float4*)&Bs[kk][tcol * 8];
            *(float4*)(b + 4) = *(const float4*)&Bs[kk][tcol * 8 + 4];
#pragma unroll
            for (int i = 0; i < 8; ++i)
#pragma unroll
                for (int j = 0; j < 8; ++j)
                    acc[i][j] = fmaf(a[i], b[j], acc[i][j]);
        }
    }

    const int nb = n0 + tcol * 8;
    const int op = nb & 1023;
#pragma unroll
    for (int i = 0; i < 8; ++i) {
        int co = co0 + trow * 8 + i;
        if (remap && co >= 384) co += 384;
        float* o = out + (((size_t)bidx * cout_stride + co_off + co) << 10) + op;
        float v[8];
#pragma unroll
        for (int j = 0; j < 8; ++j) v[j] = acc[i][j];
        if (accumulate) {
#pragma unroll
            for (int j = 0; j < 8; ++j) v[j] += o[j];
        }
        *(float4*)(o)     = make_float4(v[0], v[1], v[2], v[3]);
        *(float4*)(o + 4) = make_float4(v[4], v[5], v[6], v[7]);
    }
}

// net = msk*frame + (1-msk)*x_gen  (transpose BTHWC -> BCHW)
__global__ __launch_bounds__(256) void net_kernel(
    const float* __restrict__ frames, const float* __restrict__ mask,
    const float* __restrict__ xgen, float* __restrict__ net, int t)
{
    const int idx = blockIdx.x * 256 + threadIdx.x;   // B*16*1024
    const int p = idx & 1023;
    const int ch = (idx >> 10) & 15;
    const int b = idx >> 14;
    const float fr = frames[((((size_t)b * 20 + t) << 10) + p) * 16 + ch];
    float v;
    if (t < TPREV) {
        v = fr;
    } else {
        const float mk = mask[((((size_t)b * 9 + (t - TPREV)) << 10) + p) * 16 + ch];
        v = mk * fr + (1.f - mk) * xgen[idx];
    }
    net[idx] = v;
}

// gates: preact chunks (x128 ch): i@0 f@1 g@2 i'@3 f'@4 g'@5 o@6
__global__ __launch_bounds__(256) void gates_kernel(
    const float* __restrict__ pre, float* __restrict__ c,
    float* __restrict__ m, float* __restrict__ mem)
{
    const int idx = blockIdx.x * 256 + threadIdx.x;   // B*128*1024
    const int p = idx & 1023;
    const int ch = (idx >> 10) & 127;
    const int b = idx >> 17;
    const float* pb = pre + (((size_t)b * 896 + ch) << 10) + p;
    const float i_ = pb[0];
    const float f_ = pb[(size_t)128 << 10];
    const float g_ = pb[(size_t)256 << 10];
    const float ip = pb[(size_t)384 << 10];
    const float fp = pb[(size_t)512 << 10];
    const float gp = pb[(size_t)640 << 10];
    const float cold = c[idx];
    const float mold = m[idx];
    const float cn = sigmoidf_(f_ + 1.f) * cold + sigmoidf_(i_) * tanhf(g_);
    const float mn = sigmoidf_(fp + 1.f) * mold + sigmoidf_(ip) * tanhf(gp);
    c[idx] = cn;
    m[idx] = mn;
    const size_t memi = (((size_t)b * 256 + ch) << 10) + p;
    mem[memi] = cn;
    mem[memi + ((size_t)128 << 10)] = mn;
}

// h = sigmoid(o_pre + oconv) * tanh(lconv)
__global__ __launch_bounds__(256) void hout_kernel(
    const float* __restrict__ pre, const float* __restrict__ oconv,
    const float* __restrict__ lconv, float* __restrict__ h)
{
    const int idx = blockIdx.x * 256 + threadIdx.x;   // B*128*1024
    const int p = idx & 1023;
    const int ch = (idx >> 10) & 127;
    const int b = idx >> 17;
    const float o_pre = pre[(((size_t)b * 896 + 768 + ch) << 10) + p];
    const float ot = sigmoidf_(o_pre + oconv[idx]);
    h[idx] = ot * tanhf(lconv[idx]);
}

// x_gen = Wout(1x1) . h3 ; also scatter to d_out [B,T,H,W,C]
__global__ __launch_bounds__(256) void wout_kernel(
    const float* __restrict__ h3, const float* __restrict__ wo,
    float* __restrict__ xgen, float* __restrict__ out, int t)
{
    const int idx = blockIdx.x * 256 + threadIdx.x;   // B*16*1024
    const int p = idx & 1023;
    const int ch = (idx >> 10) & 15;
    const int b = idx >> 14;
    const float* hb = h3 + ((size_t)b << 17);
    const float* wr = wo + ch * 128;
    float acc = 0.f;
#pragma unroll 4
    for (int ci = 0; ci < 128; ++ci)
        acc = fmaf(hb[(ci << 10) + p], wr[ci], acc);
    xgen[idx] = acc;
    out[((((size_t)b * TT + t) << 10) + p) * 16 + ch] = acc;
}

extern "C" void kernel_launch(void* const* d_in, const int* in_sizes, int n_in,
                              void* d_out, int out_size, void* d_ws, size_t ws_size,
                              hipStream_t stream)
{
    const float* frames = (const float*)d_in[0];
    const float* mask   = (const float*)d_in[1];
    const float* Wx0    = (const float*)d_in[2];
    const float* Wx     = (const float*)d_in[3];
    const float* Wh     = (const float*)d_in[4];
    const float* Wm     = (const float*)d_in[5];
    const float* Wo     = (const float*)d_in[6];
    const float* Wl     = (const float*)d_in[7];
    const float* Wout   = (const float*)d_in[8];
    float* out = (float*)d_out;
    float* ws = (float*)d_ws;

    const size_t SZ_LAYER = (size_t)BB * NH * PLANE;        // 1,048,576
    float* h    = ws;                                       // [L][B,128,32,32]
    float* c    = h    + NL * SZ_LAYER;                     // [L][...]
    float* m    = c    + NL * SZ_LAYER;                     // [B,128,...]
    float* xgen = m    + SZ_LAYER;                          // [B,16,...]
    float* net  = xgen + (size_t)BB * FC * PLANE;
    float* pre  = net  + (size_t)BB * FC * PLANE;           // [B,896,...]
    float* mem  = pre  + (size_t)BB * 896 * PLANE;          // [B,256,...]
    float* oconv= mem  + (size_t)BB * 256 * PLANE;          // [B,128,...]
    float* lconv= oconv+ SZ_LAYER;                          // [B,128,...]

    // zero h, c, m (contiguous prefix)
    hipMemsetAsync(ws, 0, (2 * NL * SZ_LAYER + SZ_LAYER) * sizeof(float), stream);

    for (int t = 0; t < TT; ++t) {
        net_kernel<<<512, 256, 0, stream>>>(frames, mask, xgen, net, t);
        for (int l = 0; l < NL; ++l) {
            const float* x = (l == 0) ? net : (h + (size_t)(l - 1) * SZ_LAYER);
            const int cin_x = (l == 0) ? FC : NH;
            const float* wx = (l == 0) ? Wx0 : (Wx + (size_t)(l - 1) * 896 * 128 * 25);
            // phase A: gate pre-activations -> pre[B,896,..]
            // xc: natural order i f g i' f' g' o  (chunks 0..6)
            conv_gemm_kernel<5><<<dim3(64, 7), 256, 0, stream>>>(
                x, wx, pre, cin_x, 0, 896, 0, 0);
            // hc: i f g at 0..383, o_h remapped to 768..895
            conv_gemm_kernel<5><<<dim3(64, 4), 256, 0, stream>>>(
                h + (size_t)l * SZ_LAYER, Wh + (size_t)l * 512 * 128 * 25,
                pre, 128, 0, 896, 1, 1);
            // mc: i' f' g' at 384..767
            conv_gemm_kernel<5><<<dim3(64, 3), 256, 0, stream>>>(
                m, Wm + (size_t)l * 384 * 128 * 25, pre, 128, 384, 896, 1, 0);
            // gates -> c[l], m, mem=[c_new;m_new]
            gates_kernel<<<4096, 256, 0, stream>>>(pre, c + (size_t)l * SZ_LAYER, m, mem);
            // phase B
            conv_gemm_kernel<5><<<dim3(64, 1), 256, 0, stream>>>(
                mem, Wo + (size_t)l * 128 * 256 * 25, oconv, 256, 0, 128, 0, 0);
            conv_gemm_kernel<1><<<dim3(64, 1), 256, 0, stream>>>(
                mem, Wl + (size_t)l * 128 * 256, lconv, 256, 0, 128, 0, 0);
            hout_kernel<<<4096, 256, 0, stream>>>(pre, oconv, lconv, h + (size_t)l * SZ_LAYER);
        }
        wout_kernel<<<512, 256, 0, stream>>>(h + (size_t)3 * SZ_LAYER, Wout, xgen, out, t);
    }
}

// Round 2
// 19645.494 us; speedup vs baseline: 10.8784x; 10.8784x over previous
//
#include <hip/hip_runtime.h>
#include <math.h>

#define TT 19
#define TPREV 10

typedef __attribute__((ext_vector_type(8))) short bf8v;
typedef __attribute__((ext_vector_type(4))) float f4v;

__device__ __forceinline__ float sigmoidf_(float x){ return 1.f/(1.f+expf(-x)); }
__device__ __forceinline__ unsigned short f2bf(float x){
    unsigned int u = __float_as_uint(x);
    u += 0x7FFFu + ((u>>16)&1u);
    return (unsigned short)(u>>16);
}
__device__ __forceinline__ float bf2f(unsigned short b){ return __uint_as_float(((unsigned int)b)<<16); }

__device__ __forceinline__ void glds16(const unsigned short* g, unsigned short* l){
    __builtin_amdgcn_global_load_lds(
        (const __attribute__((address_space(1))) void*)g,
        (__attribute__((address_space(3))) void*)l, 16, 0, 0);
}

// ------------------------------------------------------------------
// job = one 128-row (Cout) slice of one conv GEMM over N=8192
// ------------------------------------------------------------------
struct ConvJob {
    const unsigned short* in;   // NHWC bf16 [8][1024][Cin]
    const unsigned short* w;    // packed bf16 [128][wstride] (tap-major, ci-minor)
    float* out;                 // f32 NHWC, pre-offset by co_base
    int wstride, k0, k1, cin_log2, five, cout_stride, accum;
};
struct ConvJobs { ConvJob j[8]; };

__global__ __launch_bounds__(256) void conv_mfma_kernel(ConvJobs jobs, const unsigned short* zp)
{
    __shared__ unsigned short sA[4096];
    __shared__ unsigned short sB[4096];
    const ConvJob jb = jobs.j[blockIdx.y];
    const int tid = threadIdx.x;
    const int cl = jb.cin_log2;
    const int cinm = (1 << cl) - 1;
    const int five = jb.five;
    const int ntaps = five ? 25 : 1;

    // staging: thread handles chunks c=tid and c=tid+256; c = q*128 + row
    const int rA = tid & 127;
    const int q1 = tid >> 7;            // second chunk: q1+2
    const unsigned short* wrow = jb.w + (size_t)rA * jb.wstride;

    const int ng = blockIdx.x * 128 + rA;
    const int bb = ng >> 10, pp = ng & 1023;
    const int py = pp >> 5, px = pp & 31;
    const unsigned short* inb = jb.in + ((size_t)bb << (10 + cl));

    unsigned short* ldsA1 = &sA[tid * 8];
    unsigned short* ldsA2 = &sA[(tid + 256) * 8];
    unsigned short* ldsB1 = &sB[tid * 8];
    unsigned short* ldsB2 = &sB[(tid + 256) * 8];

    const int lane = tid & 63, wv = tid >> 6;
    const int wm = (wv & 1) << 6;       // wave m-offset
    const int wn = (wv >> 1) << 6;      // wave n-offset
    const int qq = lane >> 4, rr = lane & 15;

    f4v acc[4][4];
#pragma unroll
    for (int i = 0; i < 4; ++i)
#pragma unroll
        for (int j = 0; j < 4; ++j) acc[i][j] = (f4v)0.f;

    for (int k = jb.k0; k < jb.k1; k += 32) {
        // ---- A (weights): rows contiguous in K
        glds16(wrow + k + q1 * 8, ldsA1);
        glds16(wrow + k + q1 * 8 + 16, ldsA2);
        // ---- B (im2col gather), chunk q = q1 and q1+2
#pragma unroll
        for (int cc = 0; cc < 2; ++cc) {
            const int q = q1 + cc * 2;
            const int kk = k + q * 8;
            const int tap = kk >> cl;
            const int ci = kk & cinm;
            int dy = 0, dx = 0;
            if (five) { const int t5 = (tap * 52) >> 8; dy = t5 - 2; dx = tap - t5 * 5 - 2; }
            const int yy = py + dy, xx = px + dx;
            const bool ok = (tap < ntaps) & ((unsigned)yy < 32u) & ((unsigned)xx < 32u);
            const unsigned short* gp = ok ? (inb + ((((yy << 5) + xx)) << cl) + ci) : zp;
            glds16(gp, cc ? ldsB2 : ldsB1);
        }
        __syncthreads();
        bf8v av[4], bv[4];
#pragma unroll
        for (int mi = 0; mi < 4; ++mi)
            av[mi] = *(const bf8v*)&sA[(qq * 128 + wm + mi * 16 + rr) * 8];
#pragma unroll
        for (int ni = 0; ni < 4; ++ni)
            bv[ni] = *(const bf8v*)&sB[(qq * 128 + wn + ni * 16 + rr) * 8];
#pragma unroll
        for (int mi = 0; mi < 4; ++mi)
#pragma unroll
            for (int ni = 0; ni < 4; ++ni)
                acc[mi][ni] = __builtin_amdgcn_mfma_f32_16x16x32_bf16(av[mi], bv[ni], acc[mi][ni], 0, 0, 0);
        __syncthreads();
    }

    // epilogue: C/D map col=lane&15 -> n, row=(lane>>4)*4+reg -> m
    const int nfix = blockIdx.x * 128 + wn;
#pragma unroll
    for (int ni = 0; ni < 4; ++ni) {
        const int n = nfix + ni * 16 + rr;
        float* ob = jb.out + (size_t)n * jb.cout_stride + wm + qq * 4;
#pragma unroll
        for (int mi = 0; mi < 4; ++mi) {
            float* op = ob + mi * 16;
            f4v v = acc[mi][ni];
            if (jb.accum) v += *(const f4v*)op;
            *(f4v*)op = v;
        }
    }
}

// ------------------------------------------------------------------
// weight pack: OIHW f32 -> [co][tap][ci] bf16, taps padded
// ------------------------------------------------------------------
__global__ __launch_bounds__(256) void pack_kernel(
    const float* __restrict__ src, unsigned short* __restrict__ dst,
    int cilog2, int tapsPad, int srcTaps, int total)
{
    const int idx = blockIdx.x * 256 + threadIdx.x;
    if (idx >= total) return;
    const int ci = idx & ((1 << cilog2) - 1);
    const int t2 = idx >> cilog2;
    const int tap = t2 % tapsPad;
    const int co = t2 / tapsPad;
    float v = 0.f;
    if (tap < srcTaps)
        v = src[((size_t)(co << cilog2) + ci) * srcTaps + tap];
    dst[idx] = f2bf(v);
}

// net = msk*frame + (1-msk)*x_gen  -> bf16 NHWC
__global__ __launch_bounds__(256) void net_kernel(
    const float* __restrict__ frames, const float* __restrict__ mask,
    const float* __restrict__ xgen, unsigned short* __restrict__ net, int t)
{
    const int idx = blockIdx.x * 256 + threadIdx.x;  // 8192*16
    const int n = idx >> 4, ch = idx & 15;
    const int b = n >> 10, p = n & 1023;
    const float fr = frames[((((size_t)b * 20 + t) << 10) + p) * 16 + ch];
    float v;
    if (t < TPREV) v = fr;
    else {
        const float mk = mask[((((size_t)b * 9 + (t - TPREV)) << 10) + p) * 16 + ch];
        v = mk * fr + (1.f - mk) * xgen[idx];
    }
    net[idx] = f2bf(v);
}

// gates from pre (NHWC [n][896]); updates c, m (f32), m_bf, mem (bf16)
__global__ __launch_bounds__(256) void gates_kernel(
    const float* __restrict__ pre, float* __restrict__ c, float* __restrict__ m,
    unsigned short* __restrict__ m_bf, unsigned short* __restrict__ mem)
{
    const int idx = blockIdx.x * 256 + threadIdx.x;  // 8192*128
    const int n = idx >> 7, ch = idx & 127;
    const float* pn = pre + (size_t)n * 896 + ch;
    const float i_ = pn[0];
    const float f_ = pn[128];
    const float g_ = pn[256];
    const float ip = pn[384];
    const float fp = pn[512];
    const float gp = pn[640];
    const float cn = sigmoidf_(f_ + 1.f) * c[idx] + sigmoidf_(i_) * tanhf(g_);
    const float mn = sigmoidf_(fp + 1.f) * m[idx] + sigmoidf_(ip) * tanhf(gp);
    c[idx] = cn;
    m[idx] = mn;
    m_bf[idx] = f2bf(mn);
    mem[(size_t)n * 256 + ch] = f2bf(cn);
    mem[(size_t)n * 256 + 128 + ch] = f2bf(mn);
}

// h = sigmoid(o_pre + sum oconv partials) * tanh(lconv) -> bf16
__global__ __launch_bounds__(256) void hout_kernel(
    const float* __restrict__ pre, const float* __restrict__ opart,
    const float* __restrict__ lconv, unsigned short* __restrict__ h)
{
    const int idx = blockIdx.x * 256 + threadIdx.x;  // 8192*128
    const int n = idx >> 7, ch = idx & 127;
    float oc = opart[idx] + opart[idx + 1048576] + opart[idx + 2097152] + opart[idx + 3145728];
    oc += pre[(size_t)n * 896 + 768 + ch];
    h[idx] = f2bf(sigmoidf_(oc) * tanhf(lconv[idx]));
}

// x_gen = Wout(1x1) . h3; scatter to d_out
__global__ __launch_bounds__(256) void wout_kernel(
    const unsigned short* __restrict__ h3, const float* __restrict__ wo,
    float* __restrict__ xgen, float* __restrict__ out, int t)
{
    const int idx = blockIdx.x * 256 + threadIdx.x;  // 8192*16
    const int n = idx >> 4, ch = idx & 15;
    const int b = n >> 10, p = n & 1023;
    const unsigned short* hr = h3 + (size_t)n * 128;
    const float* wr = wo + ch * 128;
    float acc = 0.f;
#pragma unroll 8
    for (int ci = 0; ci < 128; ++ci)
        acc = fmaf(bf2f(hr[ci]), wr[ci], acc);
    xgen[idx] = acc;
    out[((((size_t)b * TT + t) << 10) + p) * 16 + ch] = acc;
}

extern "C" void kernel_launch(void* const* d_in, const int* in_sizes, int n_in,
                              void* d_out, int out_size, void* d_ws, size_t ws_size,
                              hipStream_t stream)
{
    const float* frames = (const float*)d_in[0];
    const float* mask   = (const float*)d_in[1];
    const float* Wx0    = (const float*)d_in[2];
    const float* Wx     = (const float*)d_in[3];
    const float* Wh     = (const float*)d_in[4];
    const float* Wm     = (const float*)d_in[5];
    const float* Wo     = (const float*)d_in[6];
    const float* Wl     = (const float*)d_in[7];
    const float* Wout   = (const float*)d_in[8];
    float* out = (float*)d_out;

    char* base = (char*)d_ws;
    size_t off = 0;
    auto take = [&](size_t bytes) -> char* {
        char* p = base + off;
        off = (off + bytes + 255) & ~(size_t)255;
        return p;
    };
    // ---- zero-init region (c, m, h_bf, m_bf, zero page) ----
    float* c0            = (float*)take(4ull * 1048576 * 4);
    float* m32           = (float*)take((size_t)1048576 * 4);
    unsigned short* hbf  = (unsigned short*)take(4ull * 1048576 * 2);
    unsigned short* mbf  = (unsigned short*)take((size_t)1048576 * 2);
    unsigned short* zp   = (unsigned short*)take(256);
    const size_t zbytes = off;
    // ---- working buffers ----
    float* xgen          = (float*)take((size_t)131072 * 4);
    float* pre           = (float*)take((size_t)8192 * 896 * 4);
    float* lconv         = (float*)take((size_t)1048576 * 4);
    float* opart         = (float*)take(4ull * 1048576 * 4);
    unsigned short* net  = (unsigned short*)take((size_t)131072 * 2);
    unsigned short* mem  = (unsigned short*)take((size_t)2097152 * 2);
    // ---- packed weights (bf16) ----
    unsigned short* wx0p = (unsigned short*)take((size_t)372736 * 2);   // 896 x 416
    unsigned short* wxp  = (unsigned short*)take((size_t)8601600 * 2);  // 3 x 896 x 3200
    unsigned short* whp  = (unsigned short*)take((size_t)6553600 * 2);  // 4 x 512 x 3200
    unsigned short* wmp  = (unsigned short*)take((size_t)4915200 * 2);  // 4 x 384 x 3200
    unsigned short* wop  = (unsigned short*)take((size_t)3276800 * 2);  // 4 x 128 x 6400
    unsigned short* wlp  = (unsigned short*)take((size_t)131072 * 2);   // 4 x 128 x 256

    hipMemsetAsync(d_ws, 0, zbytes, stream);

    auto packl = [&](const float* s, unsigned short* d, int Co, int cilog2, int tapsPad, int srcTaps) {
        const int total = (Co * tapsPad) << cilog2;
        pack_kernel<<<(total + 255) / 256, 256, 0, stream>>>(s, d, cilog2, tapsPad, srcTaps, total);
    };
    packl(Wx0, wx0p, 896, 4, 26, 25);
    for (int l = 0; l < 3; ++l) packl(Wx + (size_t)l * 896 * 128 * 25, wxp + (size_t)l * 2867200, 896, 7, 25, 25);
    for (int l = 0; l < 4; ++l) {
        packl(Wh + (size_t)l * 512 * 128 * 25, whp + (size_t)l * 1638400, 512, 7, 25, 25);
        packl(Wm + (size_t)l * 384 * 128 * 25, wmp + (size_t)l * 1228800, 384, 7, 25, 25);
        packl(Wo + (size_t)l * 128 * 256 * 25, wop + (size_t)l * 819200, 128, 8, 25, 25);
        packl(Wl + (size_t)l * 128 * 256,      wlp + (size_t)l * 32768, 128, 8, 1, 1);
    }

    for (int t = 0; t < TT; ++t) {
        net_kernel<<<512, 256, 0, stream>>>(frames, mask, xgen, net, t);
        for (int l = 0; l < 4; ++l) {
            const unsigned short* xin = (l == 0) ? net : (hbf + (size_t)(l - 1) * 1048576);
            const unsigned short* wx  = (l == 0) ? wx0p : (wxp + (size_t)(l - 1) * 2867200);
            const int kx = (l == 0) ? 416 : 3200;
            const int clx = (l == 0) ? 4 : 7;
            unsigned short* hl = hbf + (size_t)l * 1048576;
            ConvJobs J{};

            // ---- xc: 7 jobs, write pre[.., y*128 ..]
            for (int y = 0; y < 7; ++y)
                J.j[y] = ConvJob{ xin, wx + (size_t)y * 128 * kx, pre + y * 128,
                                  kx, 0, kx, clx, 1, 896, 0 };
            conv_mfma_kernel<<<dim3(64, 7), 256, 0, stream>>>(J, zp);

            // ---- hc (4 jobs: i,f,g @0..383, o @768) + mc (3 jobs: @384..767), accumulate
            for (int y = 0; y < 4; ++y)
                J.j[y] = ConvJob{ hl, whp + (size_t)l * 1638400 + (size_t)y * 128 * 3200,
                                  pre + ((y < 3) ? y * 128 : 768),
                                  3200, 0, 3200, 7, 1, 896, 1 };
            for (int y = 0; y < 3; ++y)
                J.j[4 + y] = ConvJob{ mbf, wmp + (size_t)l * 1228800 + (size_t)y * 128 * 3200,
                                      pre + 384 + y * 128,
                                      3200, 0, 3200, 7, 1, 896, 1 };
            conv_mfma_kernel<<<dim3(64, 7), 256, 0, stream>>>(J, zp);

            gates_kernel<<<4096, 256, 0, stream>>>(pre, c0 + (size_t)l * 1048576, m32, mbf, mem);

            // ---- oconv split-K x4 + lconv
            for (int s = 0; s < 4; ++s)
                J.j[s] = ConvJob{ mem, wop + (size_t)l * 819200, opart + (size_t)s * 1048576,
                                  6400, s * 1600, (s + 1) * 1600, 8, 1, 128, 0 };
            J.j[4] = ConvJob{ mem, wlp + (size_t)l * 32768, lconv, 256, 0, 256, 8, 0, 128, 0 };
            conv_mfma_kernel<<<dim3(64, 5), 256, 0, stream>>>(J, zp);

            hout_kernel<<<4096, 256, 0, stream>>>(pre, opart, lconv, hl);
        }
        wout_kernel<<<512, 256, 0, stream>>>(hbf + (size_t)3 * 1048576, Wout, xgen, out, t);
    }
}

// Round 5
// 18369.826 us; speedup vs baseline: 11.6338x; 1.0694x over previous
//
#include <hip/hip_runtime.h>
#include <math.h>

#define TT 19
#define TPREV 10

typedef __attribute__((ext_vector_type(8))) short bf8v;
typedef __attribute__((ext_vector_type(4))) float f4v;

__device__ __forceinline__ float sigmoidf_(float x){ return 1.f/(1.f+expf(-x)); }
__device__ __forceinline__ unsigned short f2bf(float x){
    unsigned int u = __float_as_uint(x);
    u += 0x7FFFu + ((u>>16)&1u);
    return (unsigned short)(u>>16);
}
__device__ __forceinline__ float bf2f(unsigned short b){ return __uint_as_float(((unsigned int)b)<<16); }

// NOTE (R4): NEVER use the offset-immediate arg of global_load_lds here —
// on LDS-DMA instructions the imm offset may be added to the LDS address as
// well as the global address (Vega ISA lineage), which silently misplaces
// staged chunks. Always offset=0 + explicit pointer arithmetic (R2-proven).
#define GLDS(g, l) __builtin_amdgcn_global_load_lds( \
    (const __attribute__((address_space(1))) void*)(g),   \
    (__attribute__((address_space(3))) void*)(l), 16, 0, 0)

// ------------------------------------------------------------------
// Segmented implicit-GEMM conv over concatenated K.
// Inputs NHWC bf16 [8][1024][Cin]; weights packed bf16 [128 rows][wstride],
// row = [seg0: tap-major ci-minor | seg1: ...]. Output f32 [n][cout_stride].
// Weight column for (tap, c) = kbase + (tap - tap_lo)*Cin + c.
// ------------------------------------------------------------------
struct Seg {
    const unsigned short* in;
    int cl;        // log2(Cin)
    int tap_lo, tap_hi;
    int kbase;     // column offset in weight row where tap_lo starts
    int five;      // 5x5 (else 1x1)
};
struct Job {
    const unsigned short* w;
    float* out;
    int wstride, cout_stride, nseg, pad;
    Seg s[2];
};
struct Jobs8 { Job j[8]; };

__global__ __launch_bounds__(256) void conv_mfma_kernel(Jobs8 jobs, const unsigned short* zp)
{
    __shared__ unsigned short sA[4096];
    __shared__ unsigned short sB[4096];
    const Job jb = jobs.j[blockIdx.y];
    const int tid = threadIdx.x;

    const int rA = tid & 127;
    const int q1 = tid >> 7;            // this thread stages chunks q1 and q1+2
    const unsigned short* wrow = jb.w + (size_t)rA * jb.wstride + q1 * 8;

    const int ng = blockIdx.x * 128 + rA;
    const int bb = ng >> 10, pp = ng & 1023;
    const int py = pp >> 5, px = pp & 31;

    unsigned short* ldsA1 = &sA[tid * 8];
    unsigned short* ldsA2 = &sA[(tid + 256) * 8];
    unsigned short* ldsB1 = &sB[tid * 8];
    unsigned short* ldsB2 = &sB[(tid + 256) * 8];

    const int lane = tid & 63, wv = tid >> 6;
    const int wm = (wv & 1) << 6;
    const int wn = (wv >> 1) << 6;
    const int qq = lane >> 4, rr = lane & 15;

    f4v acc[4][4];
#pragma unroll
    for (int i = 0; i < 4; ++i)
#pragma unroll
        for (int j = 0; j < 4; ++j) acc[i][j] = (f4v)0.f;

#define MFMA_STEP() do {                                                      \
        __syncthreads();                                                      \
        bf8v av[4], bv[4];                                                    \
        _Pragma("unroll")                                                     \
        for (int mi = 0; mi < 4; ++mi)                                        \
            av[mi] = *(const bf8v*)&sA[(qq * 128 + wm + mi * 16 + rr) * 8];   \
        _Pragma("unroll")                                                     \
        for (int ni = 0; ni < 4; ++ni)                                        \
            bv[ni] = *(const bf8v*)&sB[(qq * 128 + wn + ni * 16 + rr) * 8];   \
        _Pragma("unroll")                                                     \
        for (int mi = 0; mi < 4; ++mi)                                        \
            _Pragma("unroll")                                                 \
            for (int ni = 0; ni < 4; ++ni)                                    \
                acc[mi][ni] = __builtin_amdgcn_mfma_f32_16x16x32_bf16(        \
                    av[mi], bv[ni], acc[mi][ni], 0, 0, 0);                    \
        __syncthreads();                                                      \
    } while (0)

    for (int si = 0; si < jb.nseg; ++si) {
        const Seg sg = jb.s[si];
        const int cil = sg.cl;
        const unsigned short* inb = sg.in + ((size_t)bb << (10 + cil));
        if (cil >= 5) {
            // tap-outer: per-tap base pointer, inner loop pure pointer walk
            const int cin = 1 << cil;
            for (int tap = sg.tap_lo; tap < sg.tap_hi; ++tap) {
                int dy = 0, dx = 0;
                if (sg.five) { const int t5 = (tap * 52) >> 8; dy = t5 - 2; dx = tap - t5 * 5 - 2; }
                const int yy = py + dy, xx = px + dx;
                const bool ok = ((unsigned)yy < 32u) & ((unsigned)xx < 32u);
                const unsigned short* gB = ok ? (inb + ((((yy << 5) + xx)) << cil) + q1 * 8)
                                              : (zp + q1 * 8);
                // column relative to tap_lo (R3 fix)
                const unsigned short* gA = wrow + sg.kbase + ((tap - sg.tap_lo) << cil);
                for (int c = 0; c < cin; c += 32) {
                    GLDS(gA,      ldsA1);
                    GLDS(gA + 16, ldsA2);
                    GLDS(gB,      ldsB1);
                    GLDS(gB + 16, ldsB2);
                    gA += 32; gB += 32;
                    MFMA_STEP();
                }
            }
        } else {
            // cl==4 (l=0 x-segment): K = 26*16 = 416, per-chunk addressing
            for (int k = 0; k < 416; k += 32) {
                const unsigned short* gA = wrow + sg.kbase + k;
                GLDS(gA,      ldsA1);
                GLDS(gA + 16, ldsA2);
#pragma unroll
                for (int cc = 0; cc < 2; ++cc) {
                    const int kk = k + q1 * 8 + cc * 16;
                    const int tap = kk >> 4;
                    const int ci = kk & 15;
                    const int t5 = (tap * 52) >> 8;
                    const int yy = py + t5 - 2;
                    const int xx = px + (tap - t5 * 5) - 2;
                    const bool ok = (tap < 25) & ((unsigned)yy < 32u) & ((unsigned)xx < 32u);
                    const unsigned short* gp = ok ? (inb + ((((yy << 5) + xx)) << 4) + ci) : zp;
                    GLDS(gp, cc ? ldsB2 : ldsB1);
                }
                MFMA_STEP();
            }
        }
    }

    // epilogue: col = lane&15 -> n, row = (lane>>4)*4 + reg -> m
    const int nfix = blockIdx.x * 128 + wn;
#pragma unroll
    for (int ni = 0; ni < 4; ++ni) {
        const int n = nfix + ni * 16 + rr;
        float* ob = jb.out + (size_t)n * jb.cout_stride + wm + qq * 4;
#pragma unroll
        for (int mi = 0; mi < 4; ++mi)
            *(f4v*)(ob + mi * 16) = acc[mi][ni];
    }
}

// ------------------------------------------------------------------
// pack: src [Co][Cin][srcTaps] f32 -> dst rows [dstRowBase+co][dstStride],
// columns dstColOff + tap*Cin + ci (bf16), taps >= srcTaps zero-padded
// ------------------------------------------------------------------
__global__ __launch_bounds__(256) void pack_kernel(
    const float* __restrict__ src, unsigned short* __restrict__ dst,
    int cl, int tapsPad, int srcTaps, int dstStride, int dstColOff,
    int dstRowBase, int total)
{
    const int idx = blockIdx.x * 256 + threadIdx.x;
    if (idx >= total) return;
    const int ci = idx & ((1 << cl) - 1);
    const int t2 = idx >> cl;
    const int tap = t2 % tapsPad;
    const int co = t2 / tapsPad;
    float v = 0.f;
    if (tap < srcTaps)
        v = src[((size_t)(co << cl) + ci) * srcTaps + tap];
    dst[(size_t)(dstRowBase + co) * dstStride + dstColOff + (tap << cl) + ci] = f2bf(v);
}

__global__ __launch_bounds__(256) void net_kernel(
    const float* __restrict__ frames, const float* __restrict__ mask,
    const float* __restrict__ xgen, unsigned short* __restrict__ net, int t)
{
    const int idx = blockIdx.x * 256 + threadIdx.x;  // 8192*16
    const int n = idx >> 4, ch = idx & 15;
    const int b = n >> 10, p = n & 1023;
    const float fr = frames[((((size_t)b * 20 + t) << 10) + p) * 16 + ch];
    float v;
    if (t < TPREV) v = fr;
    else {
        const float mk = mask[((((size_t)b * 9 + (t - TPREV)) << 10) + p) * 16 + ch];
        v = mk * fr + (1.f - mk) * xgen[idx];
    }
    net[idx] = f2bf(v);
}

__global__ __launch_bounds__(256) void gates_kernel(
    const float* __restrict__ pre, float* __restrict__ c, float* __restrict__ m,
    unsigned short* __restrict__ m_bf, unsigned short* __restrict__ mem)
{
    const int idx = blockIdx.x * 256 + threadIdx.x;  // 8192*128
    const int n = idx >> 7, ch = idx & 127;
    const float* pn = pre + (size_t)n * 896 + ch;
    const float i_ = pn[0];
    const float f_ = pn[128];
    const float g_ = pn[256];
    const float ip = pn[384];
    const float fp = pn[512];
    const float gp = pn[640];
    const float cn = sigmoidf_(f_ + 1.f) * c[idx] + sigmoidf_(i_) * tanhf(g_);
    const float mn = sigmoidf_(fp + 1.f) * m[idx] + sigmoidf_(ip) * tanhf(gp);
    c[idx] = cn;
    m[idx] = mn;
    m_bf[idx] = f2bf(mn);
    mem[(size_t)n * 256 + ch] = f2bf(cn);
    mem[(size_t)n * 256 + 128 + ch] = f2bf(mn);
}

__global__ __launch_bounds__(256) void hout_kernel(
    const float* __restrict__ pre, const float* __restrict__ opart,
    const float* __restrict__ lconv, unsigned short* __restrict__ h)
{
    const int idx = blockIdx.x * 256 + threadIdx.x;  // 8192*128
    const int n = idx >> 7, ch = idx & 127;
    float oc = pre[(size_t)n * 896 + 768 + ch];
#pragma unroll
    for (int j = 0; j < 7; ++j) oc += opart[idx + (size_t)j * 1048576];
    h[idx] = f2bf(sigmoidf_(oc) * tanhf(lconv[idx]));
}

__global__ __launch_bounds__(256) void wout_kernel(
    const unsigned short* __restrict__ h3, const float* __restrict__ wo,
    float* __restrict__ xgen, float* __restrict__ out, int t)
{
    const int idx = blockIdx.x * 256 + threadIdx.x;  // 8192*16
    const int n = idx >> 4, ch = idx & 15;
    const int b = n >> 10, p = n & 1023;
    const unsigned short* hr = h3 + (size_t)n * 128;
    const float* wr = wo + ch * 128;
    float acc = 0.f;
#pragma unroll 8
    for (int ci = 0; ci < 128; ++ci)
        acc = fmaf(bf2f(hr[ci]), wr[ci], acc);
    xgen[idx] = acc;
    out[((((size_t)b * TT + t) << 10) + p) * 16 + ch] = acc;
}

extern "C" void kernel_launch(void* const* d_in, const int* in_sizes, int n_in,
                              void* d_out, int out_size, void* d_ws, size_t ws_size,
                              hipStream_t stream)
{
    const float* frames = (const float*)d_in[0];
    const float* mask   = (const float*)d_in[1];
    const float* Wx0    = (const float*)d_in[2];
    const float* Wx     = (const float*)d_in[3];
    const float* Wh     = (const float*)d_in[4];
    const float* Wm     = (const float*)d_in[5];
    const float* Wo     = (const float*)d_in[6];
    const float* Wl     = (const float*)d_in[7];
    const float* Wout   = (const float*)d_in[8];
    float* out = (float*)d_out;

    char* base = (char*)d_ws;
    size_t off = 0;
    auto take = [&](size_t bytes) -> char* {
        char* p = base + off;
        off = (off + bytes + 255) & ~(size_t)255;
        return p;
    };
    // ---- zero-init region ----
    float* c0            = (float*)take(4ull * 1048576 * 4);
    float* m32           = (float*)take((size_t)1048576 * 4);
    unsigned short* hbf  = (unsigned short*)take(4ull * 1048576 * 2);
    unsigned short* mbf  = (unsigned short*)take((size_t)1048576 * 2);
    unsigned short* zp   = (unsigned short*)take(1024);
    const size_t zbytes = off;
    // ---- working buffers ----
    float* xgen          = (float*)take((size_t)131072 * 4);
    float* pre           = (float*)take((size_t)8192 * 896 * 4);
    float* lconv         = (float*)take((size_t)1048576 * 4);
    float* opart         = (float*)take(7ull * 1048576 * 4);
    unsigned short* net  = (unsigned short*)take((size_t)131072 * 2);
    unsigned short* mem  = (unsigned short*)take((size_t)2097152 * 2);
    // ---- packed weights ----
    // PA[l]: [896][K_l], K_0 = 416+3200 = 3616, K_{1..3} = 3200+3200 = 6400
    unsigned short* pa0  = (unsigned short*)take((size_t)896 * 3616 * 2);
    unsigned short* pa1  = (unsigned short*)take((size_t)896 * 6400 * 2);
    unsigned short* pa2  = (unsigned short*)take((size_t)896 * 6400 * 2);
    unsigned short* pa3  = (unsigned short*)take((size_t)896 * 6400 * 2);
    unsigned short* pal[4] = { pa0, pa1, pa2, pa3 };
    unsigned short* wop  = (unsigned short*)take(4ull * 128 * 6400 * 2);
    unsigned short* wlp  = (unsigned short*)take(4ull * 128 * 256 * 2);

    hipMemsetAsync(d_ws, 0, zbytes, stream);

    auto pack = [&](const float* s, unsigned short* d, int Co, int cl, int tapsPad,
                    int srcTaps, int stride, int colOff, int rowBase) {
        const int total = (Co * tapsPad) << cl;
        pack_kernel<<<(total + 255) / 256, 256, 0, stream>>>(
            s, d, cl, tapsPad, srcTaps, stride, colOff, rowBase, total);
    };
    // phase-A packs
    pack(Wx0, pa0, 896, 4, 26, 25, 3616, 0, 0);
    for (int l = 1; l < 4; ++l)
        pack(Wx + (size_t)(l - 1) * 896 * 128 * 25, pal[l], 896, 7, 25, 25, 6400, 0, 0);
    for (int l = 0; l < 4; ++l) {
        const int Kl = (l == 0) ? 3616 : 6400;
        const int Kx = (l == 0) ? 416 : 3200;
        const float* whl = Wh + (size_t)l * 512 * 128 * 25;
        pack(whl, pal[l], 384, 7, 25, 25, Kl, Kx, 0);                       // i,f,g <- Wh[0:384]
        pack(whl + (size_t)384 * 128 * 25, pal[l], 128, 7, 25, 25, Kl, Kx, 768); // o <- Wh[384:512]
        pack(Wm + (size_t)l * 384 * 128 * 25, pal[l], 384, 7, 25, 25, Kl, Kx, 384); // i',f',g'
        pack(Wo + (size_t)l * 128 * 256 * 25, wop + (size_t)l * 819200, 128, 8, 25, 25, 6400, 0, 0);
        pack(Wl + (size_t)l * 128 * 256, wlp + (size_t)l * 32768, 128, 8, 1, 1, 256, 0, 0);
    }

    const int ts[8] = {0, 4, 8, 12, 16, 19, 22, 25};

    for (int t = 0; t < TT; ++t) {
        net_kernel<<<512, 256, 0, stream>>>(frames, mask, xgen, net, t);
        for (int l = 0; l < 4; ++l) {
            const unsigned short* xin = (l == 0) ? net : (hbf + (size_t)(l - 1) * 1048576);
            const int clx = (l == 0) ? 4 : 7;
            const int Kl = (l == 0) ? 3616 : 6400;
            const int Kx = (l == 0) ? 416 : 3200;
            unsigned short* hl = hbf + (size_t)l * 1048576;

            // ---- phase A: 7 gate GEMMs over concatenated K
            Jobs8 J{};
            for (int g = 0; g < 7; ++g) {
                Job& j = J.j[g];
                j.w = pal[l] + (size_t)g * 128 * Kl;
                j.out = pre + g * 128;
                j.wstride = Kl;
                j.cout_stride = 896;
                j.nseg = 2;
                j.s[0] = Seg{ xin, clx, 0, 25, 0, 1 };
                const unsigned short* sec = (g < 3 || g == 6) ? hl : mbf;
                j.s[1] = Seg{ sec, 7, 0, 25, Kx, 1 };
            }
            conv_mfma_kernel<<<dim3(64, 7), 256, 0, stream>>>(J, zp);

            gates_kernel<<<4096, 256, 0, stream>>>(pre, c0 + (size_t)l * 1048576, m32, mbf, mem);

            // ---- phase B: oconv split-K x7 + lconv
            Jobs8 JB{};
            for (int s = 0; s < 7; ++s) {
                Job& j = JB.j[s];
                j.w = wop + (size_t)l * 819200;
                j.out = opart + (size_t)s * 1048576;
                j.wstride = 6400;
                j.cout_stride = 128;
                j.nseg = 1;
                j.s[0] = Seg{ mem, 8, ts[s], ts[s + 1], ts[s] << 8, 1 };
            }
            JB.j[7] = Job{ wlp + (size_t)l * 32768, lconv, 256, 128, 1, 0,
                           { Seg{ mem, 8, 0, 1, 0, 0 }, Seg{} } };
            conv_mfma_kernel<<<dim3(64, 8), 256, 0, stream>>>(JB, zp);

            hout_kernel<<<4096, 256, 0, stream>>>(pre, opart, lconv, hl);
        }
        wout_kernel<<<512, 256, 0, stream>>>(hbf + (size_t)3 * 1048576, Wout, xgen, out, t);
    }
}